// Round 6
// baseline (489.484 us; speedup 1.0000x reference)
//
#include <hip/hip_runtime.h>
#include <stdint.h>

#define NB 2
#define NH 12
#define NS 2048
#define ND 64

typedef __attribute__((ext_vector_type(4))) float f32x4;
typedef __attribute__((ext_vector_type(8))) short s16x8;

__device__ __forceinline__ short f2bf(float x) {
    return __builtin_bit_cast(short, (__bf16)x);
}
__device__ __forceinline__ float bf2f(short h) {
    uint32_t u = ((uint32_t)(unsigned short)h) << 16;
    return __builtin_bit_cast(float, u);
}
__device__ __forceinline__ f32x4 mfma16(s16x8 a, s16x8 b, f32x4 c) {
    return __builtin_amdgcn_mfma_f32_16x16x32_bf16(a, b, c, 0, 0, 0);
}

// ---------- pre-pass 1: mask int32 -> bitmask, 1 MB ----------
__global__ void kbits(const int* __restrict__ maskg, uint32_t* __restrict__ bits) {
    int wi = blockIdx.x * 256 + threadIdx.x;
    const int* mp = maskg + (size_t)wi * 32;
    uint32_t v = 0;
#pragma unroll
    for (int i = 0; i < 8; i++) {
        int4 q = *(const int4*)(mp + i * 4);
        v |= ((uint32_t)(q.x != 0) << (i * 4)) | ((uint32_t)(q.y != 0) << (i * 4 + 1)) |
             ((uint32_t)(q.z != 0) << (i * 4 + 2)) | ((uint32_t)(q.w != 0) << (i * 4 + 3));
    }
    bits[wi] = v;
}

// ---------- pre-pass 2: VwT[b,h,d,k] = V[b,h,k,d]*w[k] bf16, 6.3 MB ----------
__global__ void kvwt(const float* __restrict__ Vg, const float* __restrict__ wg,
                     unsigned short* __restrict__ vwt) {
    __shared__ float tile[32][65];
    int blk = blockIdx.x;
    int bh = blk >> 6;
    int k0 = (blk & 63) * 32;
    const float* Vh = Vg + ((size_t)bh * NS + k0) * ND;
    int t = threadIdx.x;
    {
        int kk = t >> 3, c = (t & 7) * 8;
        f32x4 a = *(const f32x4*)(Vh + kk * ND + c);
        f32x4 b4 = *(const f32x4*)(Vh + kk * ND + c + 4);
        float wk = wg[k0 + kk];
#pragma unroll
        for (int j = 0; j < 4; j++) {
            tile[kk][c + j] = a[j] * wk;
            tile[kk][c + 4 + j] = b4[j] * wk;
        }
    }
    __syncthreads();
    {
        int d = t >> 2, kb2 = (t & 3) * 8;
        s16x8 o;
#pragma unroll
        for (int j = 0; j < 8; j++) o[j] = f2bf(tile[kb2 + j][d]);
        *(s16x8*)(vwt + ((size_t)bh * ND + d) * NS + k0 + kb2) = o;
    }
}

// ---------- pre-pass 3: K f32 -> bf16, 6.3 MB ----------
__global__ void kcast(const float* __restrict__ in, unsigned short* __restrict__ outp) {
    size_t t = (size_t)blockIdx.x * 256 + threadIdx.x;
    const float* p = in + t * 8;
    f32x4 a = *(const f32x4*)p;
    f32x4 b = *(const f32x4*)(p + 4);
    s16x8 o;
#pragma unroll
    for (int j = 0; j < 4; j++) {
        o[j] = f2bf(a[j]);
        o[4 + j] = f2bf(b[j]);
    }
    *(s16x8*)(outp + t * 8) = o;
}

// ---------- kernel 1: rms table. 1536 WGs x 512 thr, 32 q-rows each ----------
__global__ __launch_bounds__(512, 8) void krms(const float* __restrict__ Qg,
                                               const uint32_t* __restrict__ bitsg,
                                               const unsigned short* __restrict__ kbfg,
                                               float* __restrict__ rinvg) {
    __shared__ float red[256];
    int bid = blockIdx.x;
    int swz = (bid & 7) * 192 + (bid >> 3);
    int bh = swz >> 6, qt = swz & 63, b = bh / NH;
    int q0 = qt * 32;
    const float* Qh = Qg + (size_t)bh * NS * ND;
    const unsigned short* kbfh = kbfg + (size_t)bh * NS * ND;
    const uint32_t* bitsb = bitsg + (size_t)b * (NS * (NS / 32));
    int tid = threadIdx.x, wv = tid >> 6, lane = tid & 63, m = lane & 15, kb = lane >> 4;

    s16x8 qf[2][2];
#pragma unroll
    for (int n = 0; n < 2; n++)
#pragma unroll
        for (int ks = 0; ks < 2; ks++) {
            const float* src = Qh + (size_t)(q0 + n * 16 + m) * ND + ks * 32 + kb * 8;
            f32x4 a = *(const f32x4*)src;
            f32x4 c4 = *(const f32x4*)(src + 4);
            s16x8 f;
#pragma unroll
            for (int j = 0; j < 4; j++) {
                f[j] = f2bf(a[j] * 0.125f);
                f[4 + j] = f2bf(c4[j] * 0.125f);
            }
            qf[n][ks] = f;
        }

    float ssum[2] = {0.f, 0.f};
    for (int kc = 0; kc < 16; kc++) {
        int krow = kc * 128 + wv * 16;
        s16x8 kf[2];
#pragma unroll
        for (int ks = 0; ks < 2; ks++)
            kf[ks] = *(const s16x8*)(kbfh + (size_t)(krow + m) * ND + ks * 32 + kb * 8);
        f32x4 c0 = {0.f, 0.f, 0.f, 0.f}, c1 = {0.f, 0.f, 0.f, 0.f};
        c0 = mfma16(kf[0], qf[0][0], c0);
        c0 = mfma16(kf[1], qf[0][1], c0);
        c1 = mfma16(kf[0], qf[1][0], c1);
        c1 = mfma16(kf[1], qf[1][1], c1);
        int kcol = krow + kb * 4;
#pragma unroll
        for (int n = 0; n < 2; n++) {
            f32x4 c = n ? c1 : c0;
            uint32_t word = bitsb[(size_t)(q0 + n * 16 + m) * (NS / 32) + (kcol >> 5)];
            uint32_t keepbits = word >> (kcol & 31);
#pragma unroll
            for (int r = 0; r < 4; r++) {
                float s = c[r];
                bool keep = ((keepbits >> r) & 1u) && (s > 0.f);
                float p = keep ? s : 0.f;
                ssum[n] += p * p;
            }
        }
    }
    ssum[0] += __shfl_xor(ssum[0], 16);
    ssum[0] += __shfl_xor(ssum[0], 32);
    ssum[1] += __shfl_xor(ssum[1], 16);
    ssum[1] += __shfl_xor(ssum[1], 32);
    if (lane < 16) {
        red[wv * 32 + lane] = ssum[0];
        red[wv * 32 + 16 + lane] = ssum[1];
    }
    __syncthreads();
    if (tid < 32) {
        float s = 0.f;
#pragma unroll
        for (int i = 0; i < 8; i++) s += red[i * 32 + tid];
        rinvg[(size_t)bh * NS + q0 + tid] = 1.0f / sqrtf(s * (1.0f / NS) + 1e-6f);
    }
}

// ---------- kernel 2: p_attn stream. 12288 WGs x 256 thr, 16q x 512k each ----
// compute QK tile -> stage bf16 in LDS -> ONE barrier -> 32 KB coalesced fp32
// store burst -> exit. No stores coupled to compute loops, no vmcnt drains in
// loops; scheduler overlaps many small WGs per CU.
__global__ __launch_bounds__(256, 6) void kstream(const float* __restrict__ Qg,
                                                  const uint32_t* __restrict__ bitsg,
                                                  const unsigned short* __restrict__ kbfg,
                                                  const float* __restrict__ wg,
                                                  const float* __restrict__ rinvg,
                                                  float* __restrict__ pg) {
    __shared__ char stage[16 * 1024];
    int bid = blockIdx.x;
    int swz = (bid & 7) * (12288 / 8) + (bid >> 3);
    int kc = swz & 3, qb = (swz >> 2) & 127, bh = swz >> 9;
    int b = bh / NH;
    int q0 = qb * 16, k0 = kc * 512;
    const unsigned short* kbfh = kbfg + (size_t)bh * NS * ND;
    const uint32_t* bitsb = bitsg + (size_t)b * (NS * (NS / 32));
    float* ph = pg + ((size_t)bh * NS + q0) * NS;
    int tid = threadIdx.x, wv = tid >> 6, lane = tid & 63, m = lane & 15, kb = lane >> 4;

    s16x8 qf[2];
#pragma unroll
    for (int ks = 0; ks < 2; ks++) {
        const float* src = Qg + ((size_t)bh * NS + q0 + m) * ND + ks * 32 + kb * 8;
        f32x4 a = *(const f32x4*)src;
        f32x4 c4 = *(const f32x4*)(src + 4);
        s16x8 f;
#pragma unroll
        for (int j = 0; j < 4; j++) {
            f[j] = f2bf(a[j] * 0.125f);
            f[4 + j] = f2bf(c4[j] * 0.125f);
        }
        qf[ks] = f;
    }

#pragma unroll
    for (int h = 0; h < 8; h++) {
        int krow = k0 + wv * 128 + h * 16;
        s16x8 kf0 = *(const s16x8*)(kbfh + (size_t)(krow + m) * ND + kb * 8);
        s16x8 kf1 = *(const s16x8*)(kbfh + (size_t)(krow + m) * ND + 32 + kb * 8);
        f32x4 c = {0.f, 0.f, 0.f, 0.f};
        c = mfma16(kf0, qf[0], c);
        c = mfma16(kf1, qf[1], c);
        int kcol = krow + kb * 4;
        uint32_t word = bitsb[(size_t)(q0 + m) * (NS / 32) + (kcol >> 5)];
        uint32_t keepbits = word >> (kcol & 31);
        float p[4];
#pragma unroll
        for (int r = 0; r < 4; r++) {
            float s = c[r];
            bool keep = ((keepbits >> r) & 1u) && (s > 0.f);
            p[r] = keep ? s : 0.f;
        }
        uint2 u;
        u.x = (uint32_t)(unsigned short)f2bf(p[0]) |
              ((uint32_t)(unsigned short)f2bf(p[1]) << 16);
        u.y = (uint32_t)(unsigned short)f2bf(p[2]) |
              ((uint32_t)(unsigned short)f2bf(p[3]) << 16);
        int cb = (wv * 256 + h * 32 + kb * 8) ^ ((m & 7) << 4);
        *(uint2*)(stage + m * 1024 + cb) = u;
    }
    __syncthreads();
    {
        int r = tid >> 4, cc = tid & 15;
        float ri = rinvg[(size_t)bh * NS + q0 + r];
#pragma unroll
        for (int j = 0; j < 4; j++) {
            int c16 = cc + j * 16;
            s16x8 pv = *(const s16x8*)(stage + r * 1024 + ((c16 * 16) ^ ((r & 7) << 4)));
            int kcolg = k0 + c16 * 8;
            f32x4 w4a = *(const f32x4*)(wg + kcolg);
            f32x4 w4b = *(const f32x4*)(wg + kcolg + 4);
            f32x4 o1, o2;
#pragma unroll
            for (int jj = 0; jj < 4; jj++) {
                o1[jj] = bf2f(pv[jj]) * w4a[jj] * ri;
                o2[jj] = bf2f(pv[4 + jj]) * w4b[jj] * ri;
            }
            float* dst = ph + (size_t)r * NS + kcolg;
            *(f32x4*)dst = o1;
            *(f32x4*)(dst + 4) = o2;
        }
    }
}

// ---------- kernel 3: PV. 1536 WGs x 512 thr, 32 q-rows each ----------
__global__ __launch_bounds__(512, 4) void kpv(const float* __restrict__ Qg,
                                              const uint32_t* __restrict__ bitsg,
                                              const unsigned short* __restrict__ kbfg,
                                              const unsigned short* __restrict__ vwtg,
                                              const float* __restrict__ rinvg,
                                              float* __restrict__ outg) {
    __shared__ char stage2[2][16384];
    int bid = blockIdx.x;
    int swz = (bid & 7) * 192 + (bid >> 3);
    int bh = swz >> 6, qt = swz & 63, b = bh / NH;
    int q0 = qt * 32;
    const float* Qh = Qg + (size_t)bh * NS * ND;
    const unsigned short* kbfh = kbfg + (size_t)bh * NS * ND;
    const uint32_t* bitsb = bitsg + (size_t)b * (NS * (NS / 32));
    float* outh = outg + (size_t)bh * NS * ND;
    int tid = threadIdx.x, wv = tid >> 6, lane = tid & 63, m = lane & 15, kb = lane >> 4;

    s16x8 qf[2][2];
#pragma unroll
    for (int n = 0; n < 2; n++)
#pragma unroll
        for (int ks = 0; ks < 2; ks++) {
            const float* src = Qh + (size_t)(q0 + n * 16 + m) * ND + ks * 32 + kb * 8;
            f32x4 a = *(const f32x4*)src;
            f32x4 c4 = *(const f32x4*)(src + 4);
            s16x8 f;
#pragma unroll
            for (int j = 0; j < 4; j++) {
                f[j] = f2bf(a[j] * 0.125f);
                f[4 + j] = f2bf(c4[j] * 0.125f);
            }
            qf[n][ks] = f;
        }

    auto qk_stage = [&](int c, char* sbuf) {
#pragma unroll
        for (int h = 0; h < 2; h++) {
            const int kc = 2 * c + h;
            int krow = kc * 128 + wv * 16;
            s16x8 kf[2];
#pragma unroll
            for (int ks = 0; ks < 2; ks++)
                kf[ks] = *(const s16x8*)(kbfh + (size_t)(krow + m) * ND + ks * 32 + kb * 8);
            f32x4 c0 = {0.f, 0.f, 0.f, 0.f}, c1 = {0.f, 0.f, 0.f, 0.f};
            c0 = mfma16(kf[0], qf[0][0], c0);
            c0 = mfma16(kf[1], qf[0][1], c0);
            c1 = mfma16(kf[0], qf[1][0], c1);
            c1 = mfma16(kf[1], qf[1][1], c1);
            int kcol = krow + kb * 4;
#pragma unroll
            for (int n = 0; n < 2; n++) {
                f32x4 cc = n ? c1 : c0;
                int q = n * 16 + m;
                uint32_t word = bitsb[(size_t)(q0 + q) * (NS / 32) + (kcol >> 5)];
                uint32_t keepbits = word >> (kcol & 31);
                float p[4];
#pragma unroll
                for (int r = 0; r < 4; r++) {
                    float s = cc[r];
                    bool keep = ((keepbits >> r) & 1u) && (s > 0.f);
                    p[r] = keep ? s : 0.f;
                }
                uint2 u;
                u.x = (uint32_t)(unsigned short)f2bf(p[0]) |
                      ((uint32_t)(unsigned short)f2bf(p[1]) << 16);
                u.y = (uint32_t)(unsigned short)f2bf(p[2]) |
                      ((uint32_t)(unsigned short)f2bf(p[3]) << 16);
                int cb = (h * 256 + wv * 32 + kb * 8) ^ ((q & 7) << 4);
                *(uint2*)(sbuf + q * 512 + cb) = u;
            }
        }
    };

    const int n_pv = wv >> 2;
    const int dt = wv & 3;
    f32x4 acc = {0.f, 0.f, 0.f, 0.f};

    qk_stage(0, stage2[0]);
    for (int it = 0; it < 8; it++) {
        char* buf = stage2[it & 1];
        __syncthreads();
        if (it < 7) qk_stage(it + 1, stage2[(it + 1) & 1]);
        {
            int bq = n_pv * 16 + m;
            int brow = bq * 512;
            int bxor = (bq & 7) << 4;
#pragma unroll
            for (int ks = 0; ks < 8; ks++) {
                s16x8 af = *(const s16x8*)(vwtg + ((size_t)bh * ND + dt * 16 + m) * NS +
                                           it * 256 + ks * 32 + kb * 8);
                s16x8 bfr = *(const s16x8*)(buf + brow + ((ks * 64 + kb * 16) ^ bxor));
                acc = mfma16(af, bfr, acc);
            }
        }
    }
    {
        int q = n_pv * 16 + m;
        float ri = rinvg[(size_t)bh * NS + q0 + q];
        f32x4 o = {acc[0] * ri, acc[1] * ri, acc[2] * ri, acc[3] * ri};
        *(f32x4*)(outh + (size_t)(q0 + q) * ND + dt * 16 + kb * 4) = o;
    }
}

// ---------- fallback (no workspace): simple fp32-exact per-row kernel ----------
__global__ void attn_fallback(const float* __restrict__ Qg, const float* __restrict__ Kg,
                              const float* __restrict__ Vg, const int* __restrict__ maskg,
                              const float* __restrict__ wg, float* __restrict__ outg,
                              float* __restrict__ pg) {
    __shared__ float qs[64];
    __shared__ float srow[2048];
    __shared__ float osum[64];
    __shared__ float red2[8];
    int bid = blockIdx.x;
    int bh = bid >> 11, q = bid & 2047, b = bh / NH;
    int tid = threadIdx.x;
    const float* Qr = Qg + ((size_t)bh * NS + q) * ND;
    const float* Kh = Kg + (size_t)bh * NS * ND;
    const float* Vh = Vg + (size_t)bh * NS * ND;
    const int* mrow = maskg + ((size_t)b * NS + q) * NS;
    if (tid < 64) {
        qs[tid] = Qr[tid] * 0.125f;
        osum[tid] = 0.f;
    }
    __syncthreads();
    float ss = 0.f;
    for (int k = tid; k < NS; k += 256) {
        float s = 0.f;
        const float* kr = Kh + (size_t)k * ND;
        for (int d = 0; d < ND; d++) s += qs[d] * kr[d];
        if (mrow[k] == 0 || s < 0.f) s = 0.f;
        srow[k] = s;
        ss += s * s;
    }
#pragma unroll
    for (int o = 32; o >= 1; o >>= 1) ss += __shfl_down(ss, o);
    if ((tid & 63) == 0) red2[tid >> 6] = ss;
    __syncthreads();
    float ri;
    {
        float tot = red2[0] + red2[1] + red2[2] + red2[3];
        ri = 1.0f / sqrtf(tot * (1.0f / NS) + 1e-6f);
    }
    for (int k = tid; k < NS; k += 256) {
        float pa = srow[k] * ri * wg[k];
        pg[(((size_t)bh * NS + q) * NS) + k] = pa;
        const float* vr = Vh + (size_t)k * ND;
        for (int d = 0; d < ND; d++) atomicAdd(&osum[d], pa * vr[d]);
    }
    __syncthreads();
    if (tid < 64) outg[((size_t)bh * NS + q) * ND + tid] = osum[tid];
}

extern "C" void kernel_launch(void* const* d_in, const int* in_sizes, int n_in,
                              void* d_out, int out_size, void* d_ws, size_t ws_size,
                              hipStream_t stream) {
    const float* Q = (const float*)d_in[0];
    const float* K = (const float*)d_in[1];
    const float* V = (const float*)d_in[2];
    const int* mask = (const int*)d_in[3];
    const float* w = (const float*)d_in[4];
    float* out = (float*)d_out;
    float* pattn = out + (size_t)NB * NH * NS * ND;

    const size_t bits_bytes = (size_t)NB * NS * (NS / 32) * sizeof(uint32_t);     // 1 MB
    const size_t vwt_bytes = (size_t)NB * NH * ND * NS * sizeof(unsigned short);  // 6.3 MB
    const size_t kbf_bytes = vwt_bytes;                                           // 6.3 MB
    const size_t rinv_bytes = (size_t)NB * NH * NS * sizeof(float);               // 196 KB

    if (ws_size >= bits_bytes + vwt_bytes + kbf_bytes + rinv_bytes) {
        char* wsb = (char*)d_ws;
        uint32_t* bits = (uint32_t*)wsb;
        unsigned short* vwt = (unsigned short*)(wsb + bits_bytes);
        unsigned short* kbf = (unsigned short*)(wsb + bits_bytes + vwt_bytes);
        float* rinv = (float*)(wsb + bits_bytes + vwt_bytes + kbf_bytes);
        kbits<<<(NB * NS * NS / 32) / 256, 256, 0, stream>>>(mask, bits);
        kcast<<<(NB * NH * NS * ND) / (256 * 8), 256, 0, stream>>>(K, kbf);
        kvwt<<<NB * NH * (NS / 32), 256, 0, stream>>>(V, w, vwt);
        krms<<<1536, 512, 0, stream>>>(Q, bits, kbf, rinv);
        kstream<<<12288, 256, 0, stream>>>(Q, bits, kbf, w, rinv, pattn);
        kpv<<<1536, 512, 0, stream>>>(Q, bits, kbf, vwt, rinv, out);
    } else {
        attn_fallback<<<NB * NH * NS, 256, 0, stream>>>(Q, K, V, mask, w, out, pattn);
    }
}

// Round 7
// 357.777 us; speedup vs baseline: 1.3681x; 1.3681x over previous
//
#include <hip/hip_runtime.h>
#include <stdint.h>

#define NB 2
#define NH 12
#define NS 2048
#define ND 64

typedef __attribute__((ext_vector_type(4))) float f32x4;
typedef __attribute__((ext_vector_type(8))) short s16x8;

__device__ __forceinline__ short f2bf(float x) {
    return __builtin_bit_cast(short, (__bf16)x);
}
__device__ __forceinline__ float bf2f(short h) {
    uint32_t u = ((uint32_t)(unsigned short)h) << 16;
    return __builtin_bit_cast(float, u);
}
__device__ __forceinline__ f32x4 mfma16(s16x8 a, s16x8 b, f32x4 c) {
    return __builtin_amdgcn_mfma_f32_16x16x32_bf16(a, b, c, 0, 0, 0);
}

// ---------- pre-pass 1: mask int32 -> bitmask, 1 MB ----------
__global__ void kbits(const int* __restrict__ maskg, uint32_t* __restrict__ bits) {
    int wi = blockIdx.x * 256 + threadIdx.x;
    const int* mp = maskg + (size_t)wi * 32;
    uint32_t v = 0;
#pragma unroll
    for (int i = 0; i < 8; i++) {
        int4 q = *(const int4*)(mp + i * 4);
        v |= ((uint32_t)(q.x != 0) << (i * 4)) | ((uint32_t)(q.y != 0) << (i * 4 + 1)) |
             ((uint32_t)(q.z != 0) << (i * 4 + 2)) | ((uint32_t)(q.w != 0) << (i * 4 + 3));
    }
    bits[wi] = v;
}

// ---------- pre-pass 2: VwT[b,h,d,k] = V[b,h,k,d]*w[k] bf16, 6.3 MB ----------
__global__ void kvwt(const float* __restrict__ Vg, const float* __restrict__ wg,
                     unsigned short* __restrict__ vwt) {
    __shared__ float tile[32][65];
    int blk = blockIdx.x;
    int bh = blk >> 6;
    int k0 = (blk & 63) * 32;
    const float* Vh = Vg + ((size_t)bh * NS + k0) * ND;
    int t = threadIdx.x;
    {
        int kk = t >> 3, c = (t & 7) * 8;
        f32x4 a = *(const f32x4*)(Vh + kk * ND + c);
        f32x4 b4 = *(const f32x4*)(Vh + kk * ND + c + 4);
        float wk = wg[k0 + kk];
#pragma unroll
        for (int j = 0; j < 4; j++) {
            tile[kk][c + j] = a[j] * wk;
            tile[kk][c + 4 + j] = b4[j] * wk;
        }
    }
    __syncthreads();
    {
        int d = t >> 2, kb2 = (t & 3) * 8;
        s16x8 o;
#pragma unroll
        for (int j = 0; j < 8; j++) o[j] = f2bf(tile[kb2 + j][d]);
        *(s16x8*)(vwt + ((size_t)bh * ND + d) * NS + k0 + kb2) = o;
    }
}

// ---------- pre-pass 3: K f32 -> bf16, 6.3 MB ----------
__global__ void kcast(const float* __restrict__ in, unsigned short* __restrict__ outp) {
    size_t t = (size_t)blockIdx.x * 256 + threadIdx.x;
    const float* p = in + t * 8;
    f32x4 a = *(const f32x4*)p;
    f32x4 b = *(const f32x4*)(p + 4);
    s16x8 o;
#pragma unroll
    for (int j = 0; j < 4; j++) {
        o[j] = f2bf(a[j]);
        o[4 + j] = f2bf(b[j]);
    }
    *(s16x8*)(outp + t * 8) = o;
}

// ---------- main fused kernel: barrier-free wave-private strips ----------
// WG = 16 q-rows, 4 waves of 64. Wave wv privately owns k in [wv*512,+512):
// pass1 rms partial, then 2 chunks of 256 k: QK->bf16 -> PRIVATE 8KB LDS stage
// (lgkmcnt only, no barrier) -> PV MFMA -> 16 stores of 1 KB contiguous each.
// Barriers only at rms reduce (x2) and final out reduce (x1). 4 WGs/CU.
template <bool WS>
__global__ __launch_bounds__(256, 4) void attn_main(
    const float* __restrict__ Qg, const float* __restrict__ Kg,
    const float* __restrict__ Vg, const int* __restrict__ maskg,
    const float* __restrict__ wg, const uint32_t* __restrict__ bitsg,
    const unsigned short* __restrict__ vwtg, const unsigned short* __restrict__ kbfg,
    float* __restrict__ outg, float* __restrict__ pg) {
    extern __shared__ char smem[];
    float* red = (float*)(smem + 32768);  // [4][16]
    float* rinv_sh = red + 64;            // [16]

    int bid = blockIdx.x;
    // XCD-aware swizzle: 3072 WGs, 384 per XCD (3 heads' worth contiguous)
    int swz = (bid & 7) * 384 + (bid >> 3);
    int bh = swz >> 7;
    int qb = swz & 127;
    int b = bh / NH;
    int q0 = qb * 16;

    const float* Qh = Qg + (size_t)bh * NS * ND;
    const float* Kh = Kg + (size_t)bh * NS * ND;
    const float* Vh = Vg + (size_t)bh * NS * ND;
    const unsigned short* kbfh = WS ? kbfg + (size_t)bh * NS * ND : nullptr;
    float* outh = outg + (size_t)bh * NS * ND;
    float* ph = pg + ((size_t)bh * NS + q0) * NS;
    const int* maskb = maskg + (size_t)b * NS * NS;
    const uint32_t* bitsb = bitsg + (size_t)b * (NS * (NS / 32));

    int tid = threadIdx.x;
    int wv = tid >> 6, lane = tid & 63;
    int m = lane & 15, kb = lane >> 4;
    char* stw = smem + wv * 8192;  // wave-private stage: [16 q][256 k bf16]
    const int ks0 = wv * 512;      // this wave's k-strip base

    // Q fragments (B operand), 1/8 folded
    s16x8 qf[2];
#pragma unroll
    for (int ks = 0; ks < 2; ks++) {
        const float* src = Qh + (size_t)(q0 + m) * ND + ks * 32 + kb * 8;
        f32x4 a = *(const f32x4*)src;
        f32x4 c4 = *(const f32x4*)(src + 4);
        s16x8 f;
#pragma unroll
        for (int j = 0; j < 4; j++) {
            f[j] = f2bf(a[j] * 0.125f);
            f[4 + j] = f2bf(c4[j] * 0.125f);
        }
        qf[ks] = f;
    }

    auto load_kf = [&](int krow, s16x8 kf[2]) {
        if (WS) {
#pragma unroll
            for (int ks = 0; ks < 2; ks++)
                kf[ks] = *(const s16x8*)(kbfh + (size_t)(krow + m) * ND + ks * 32 + kb * 8);
        } else {
#pragma unroll
            for (int ks = 0; ks < 2; ks++) {
                const float* src = Kh + (size_t)(krow + m) * ND + ks * 32 + kb * 8;
                f32x4 a = *(const f32x4*)src;
                f32x4 c4 = *(const f32x4*)(src + 4);
                s16x8 f;
#pragma unroll
                for (int j = 0; j < 4; j++) {
                    f[j] = f2bf(a[j]);
                    f[4 + j] = f2bf(c4[j]);
                }
                kf[ks] = f;
            }
        }
    };
    auto keep_of = [&](int qglob, int kcol) -> uint32_t {
        if (WS) {
            uint32_t word = bitsb[(size_t)qglob * (NS / 32) + (kcol >> 5)];
            return word >> (kcol & 31);
        } else {
            const int4 mi = *(const int4*)(maskb + (size_t)qglob * NS + kcol);
            return (uint32_t)(mi.x != 0) | ((uint32_t)(mi.y != 0) << 1) |
                   ((uint32_t)(mi.z != 0) << 2) | ((uint32_t)(mi.w != 0) << 3);
        }
    };

    // ---- pass 1: rms partial over this wave's 512-k strip ----
    float ssum = 0.f;
#pragma unroll 4
    for (int kt = 0; kt < 32; kt++) {
        int krow = ks0 + kt * 16;
        s16x8 kf[2];
        load_kf(krow, kf);
        f32x4 c = {0.f, 0.f, 0.f, 0.f};
        c = mfma16(kf[0], qf[0], c);
        c = mfma16(kf[1], qf[1], c);
        int kk = krow + kb * 4;
        uint32_t keepbits = keep_of(q0 + m, kk);
#pragma unroll
        for (int r = 0; r < 4; r++) {
            float s = c[r];
            bool keep = ((keepbits >> r) & 1u) && (s > 0.f);
            float p = keep ? s : 0.f;
            ssum += p * p;
        }
    }
    ssum += __shfl_xor(ssum, 16);
    ssum += __shfl_xor(ssum, 32);
    if (lane < 16) red[wv * 16 + lane] = ssum;
    __syncthreads();
    if (tid < 16) {
        float s = red[tid] + red[16 + tid] + red[32 + tid] + red[48 + tid];
        rinv_sh[tid] = 1.0f / sqrtf(s * (1.0f / NS) + 1e-6f);
    }
    __syncthreads();

    // ---- pass 2: 2 chunks of 256 k, fully wave-private, no barriers ----
    f32x4 acc[4];
#pragma unroll
    for (int dt = 0; dt < 4; dt++) acc[dt] = (f32x4){0.f, 0.f, 0.f, 0.f};

    for (int ch = 0; ch < 2; ch++) {
        const int cbase = ks0 + ch * 256;
        // (1) QK recompute -> relu -> bf16 -> private stage
#pragma unroll 4
        for (int kt = 0; kt < 16; kt++) {
            int krow = cbase + kt * 16;
            s16x8 kf[2];
            load_kf(krow, kf);
            f32x4 c = {0.f, 0.f, 0.f, 0.f};
            c = mfma16(kf[0], qf[0], c);
            c = mfma16(kf[1], qf[1], c);
            int kk = krow + kb * 4;
            uint32_t keepbits = keep_of(q0 + m, kk);
            float p[4];
#pragma unroll
            for (int r = 0; r < 4; r++) {
                float s = c[r];
                bool keep = ((keepbits >> r) & 1u) && (s > 0.f);
                p[r] = keep ? s : 0.f;
            }
            uint2 u;
            u.x = (uint32_t)(unsigned short)f2bf(p[0]) |
                  ((uint32_t)(unsigned short)f2bf(p[1]) << 16);
            u.y = (uint32_t)(unsigned short)f2bf(p[2]) |
                  ((uint32_t)(unsigned short)f2bf(p[3]) << 16);
            *(uint2*)(stw + m * 512 + ((kt * 32 + kb * 8) ^ ((m & 7) << 4))) = u;
        }
        asm volatile("s_waitcnt lgkmcnt(0)" ::: "memory");
        __builtin_amdgcn_sched_barrier(0);

        // (2) PV from private stage (loads only - keeps store queue decoupled)
#pragma unroll
        for (int dt = 0; dt < 4; dt++) {
#pragma unroll
            for (int ks = 0; ks < 8; ks++) {
                s16x8 af;
                if (WS) {
                    af = *(const s16x8*)(vwtg + ((size_t)bh * ND + dt * 16 + m) * NS + cbase +
                                         ks * 32 + kb * 8);
                } else {
                    s16x8 a;
#pragma unroll
                    for (int j = 0; j < 8; j++) {
                        int k = cbase + ks * 32 + kb * 8 + j;
                        a[j] = f2bf(Vh[(size_t)k * ND + dt * 16 + m] * wg[k]);
                    }
                    af = a;
                }
                s16x8 bfr =
                    *(const s16x8*)(stw + m * 512 + ((ks * 64 + kb * 16) ^ ((m & 7) << 4)));
                acc[dt] = mfma16(af, bfr, acc[dt]);
            }
        }

        // (3) stream p_attn: one 1 KB perfectly-coalesced store per row
#pragma unroll 4
        for (int r = 0; r < 16; r++) {
            uint2 u = *(const uint2*)(stw + r * 512 + ((lane * 8) ^ ((r & 7) << 4)));
            float ri = rinv_sh[r];
            f32x4 w4 = *(const f32x4*)(wg + cbase + lane * 4);
            f32x4 o;
            o[0] = bf2f((short)(u.x & 0xffff)) * w4[0] * ri;
            o[1] = bf2f((short)(u.x >> 16)) * w4[1] * ri;
            o[2] = bf2f((short)(u.y & 0xffff)) * w4[2] * ri;
            o[3] = bf2f((short)(u.y >> 16)) * w4[3] * ri;
            *(f32x4*)(ph + (size_t)r * NS + cbase + lane * 4) = o;
        }
    }

    // ---- out reduce: each wave parks its partial in its own stage slot ----
    {
        float* pOw = (float*)stw;
#pragma unroll
        for (int dt = 0; dt < 4; dt++) *(f32x4*)(pOw + m * 64 + dt * 16 + kb * 4) = acc[dt];
    }
    __syncthreads();
    {
        int q = tid >> 4, d4 = (tid & 15) * 4;
        f32x4 s = {0.f, 0.f, 0.f, 0.f};
#pragma unroll
        for (int v = 0; v < 4; v++) {
            f32x4 x = *(const f32x4*)((float*)(smem + v * 8192) + q * 64 + d4);
            s[0] += x[0];
            s[1] += x[1];
            s[2] += x[2];
            s[3] += x[3];
        }
        float ri = rinv_sh[q];
        f32x4 o = {s[0] * ri, s[1] * ri, s[2] * ri, s[3] * ri};
        *(f32x4*)(outh + (size_t)(q0 + q) * ND + d4) = o;
    }
}

extern "C" void kernel_launch(void* const* d_in, const int* in_sizes, int n_in,
                              void* d_out, int out_size, void* d_ws, size_t ws_size,
                              hipStream_t stream) {
    const float* Q = (const float*)d_in[0];
    const float* K = (const float*)d_in[1];
    const float* V = (const float*)d_in[2];
    const int* mask = (const int*)d_in[3];
    const float* w = (const float*)d_in[4];
    float* out = (float*)d_out;
    float* pattn = out + (size_t)NB * NH * NS * ND;

    const size_t bits_bytes = (size_t)NB * NS * (NS / 32) * sizeof(uint32_t);     // 1 MB
    const size_t vwt_bytes = (size_t)NB * NH * ND * NS * sizeof(unsigned short);  // 6.3 MB
    const size_t kbf_bytes = vwt_bytes;                                           // 6.3 MB
    const int nwg = NB * NH * (NS / 16);        // 3072
    const int smem = 32768 + 64 * 4 + 16 * 4;   // 33088 B

    if (ws_size >= bits_bytes + vwt_bytes + kbf_bytes) {
        char* wsb = (char*)d_ws;
        uint32_t* bits = (uint32_t*)wsb;
        unsigned short* vwt = (unsigned short*)(wsb + bits_bytes);
        unsigned short* kbf = (unsigned short*)(wsb + bits_bytes + vwt_bytes);
        kbits<<<(NB * NS * NS / 32) / 256, 256, 0, stream>>>(mask, bits);
        kcast<<<(NB * NH * NS * ND) / (256 * 8), 256, 0, stream>>>(K, kbf);
        kvwt<<<NB * NH * (NS / 32), 256, 0, stream>>>(V, w, vwt);
        attn_main<true><<<nwg, 256, smem, stream>>>(Q, K, V, mask, w, bits, vwt, kbf, out,
                                                    pattn);
    } else {
        attn_main<false><<<nwg, 256, smem, stream>>>(Q, K, V, mask, w, nullptr, nullptr,
                                                     nullptr, out, pattn);
    }
}

// Round 8
// 258.649 us; speedup vs baseline: 1.8925x; 1.3833x over previous
//
#include <hip/hip_runtime.h>
#include <stdint.h>

#define NB 2
#define NH 12
#define NS 2048
#define ND 64

typedef __attribute__((ext_vector_type(4))) float f32x4;
typedef __attribute__((ext_vector_type(8))) short s16x8;

__device__ __forceinline__ short f2bf(float x) {
    return __builtin_bit_cast(short, (__bf16)x);
}
__device__ __forceinline__ float bf2f(short h) {
    uint32_t u = ((uint32_t)(unsigned short)h) << 16;
    return __builtin_bit_cast(float, u);
}
__device__ __forceinline__ f32x4 mfma16(s16x8 a, s16x8 b, f32x4 c) {
    return __builtin_amdgcn_mfma_f32_16x16x32_bf16(a, b, c, 0, 0, 0);
}

// ---------- pre-pass 1: mask int32 -> bitmask, 1 MB ----------
__global__ void kbits(const int* __restrict__ maskg, uint32_t* __restrict__ bits) {
    int wi = blockIdx.x * 256 + threadIdx.x;
    const int* mp = maskg + (size_t)wi * 32;
    uint32_t v = 0;
#pragma unroll
    for (int i = 0; i < 8; i++) {
        int4 q = *(const int4*)(mp + i * 4);
        v |= ((uint32_t)(q.x != 0) << (i * 4)) | ((uint32_t)(q.y != 0) << (i * 4 + 1)) |
             ((uint32_t)(q.z != 0) << (i * 4 + 2)) | ((uint32_t)(q.w != 0) << (i * 4 + 3));
    }
    bits[wi] = v;
}

// ---------- pre-pass 2: VwT[b,h,d,k] = V[b,h,k,d]*w[k] bf16, 6.3 MB ----------
__global__ void kvwt(const float* __restrict__ Vg, const float* __restrict__ wg,
                     unsigned short* __restrict__ vwt) {
    __shared__ float tile[32][65];
    int blk = blockIdx.x;
    int bh = blk >> 6;
    int k0 = (blk & 63) * 32;
    const float* Vh = Vg + ((size_t)bh * NS + k0) * ND;
    int t = threadIdx.x;
    {
        int kk = t >> 3, c = (t & 7) * 8;
        f32x4 a = *(const f32x4*)(Vh + kk * ND + c);
        f32x4 b4 = *(const f32x4*)(Vh + kk * ND + c + 4);
        float wk = wg[k0 + kk];
#pragma unroll
        for (int j = 0; j < 4; j++) {
            tile[kk][c + j] = a[j] * wk;
            tile[kk][c + 4 + j] = b4[j] * wk;
        }
    }
    __syncthreads();
    {
        int d = t >> 2, kb2 = (t & 3) * 8;
        s16x8 o;
#pragma unroll
        for (int j = 0; j < 8; j++) o[j] = f2bf(tile[kb2 + j][d]);
        *(s16x8*)(vwt + ((size_t)bh * ND + d) * NS + k0 + kb2) = o;
    }
}

// ---------- pre-pass 3: K f32 -> bf16, 6.3 MB ----------
__global__ void kcast(const float* __restrict__ in, unsigned short* __restrict__ outp) {
    size_t t = (size_t)blockIdx.x * 256 + threadIdx.x;
    const float* p = in + t * 8;
    f32x4 a = *(const f32x4*)p;
    f32x4 b = *(const f32x4*)(p + 4);
    s16x8 o;
#pragma unroll
    for (int j = 0; j < 4; j++) {
        o[j] = f2bf(a[j]);
        o[4 + j] = f2bf(b[j]);
    }
    *(s16x8*)(outp + t * 8) = o;
}

// ---------- main: wave-specialized producer/streamer ----------
// WG = 512 thr (8 waves), 16 q-rows. LDS: full P[16][2048] bf16 (64 KB,
// XOR (m&7)<<4) + w copy (8 KB) + reduce scratch. 2 WGs/CU.
// Phase 1 (all 8 waves): QK over own 256-k strip -> relu/mask -> bf16 P in
// LDS + ssum partial. One barrier; rinv.
// Phase 2: waves 0-3: PV MFMA over full k for own 16-d tile -> out; then
// stream 1 p_attn row. Waves 4-7: PURE STREAMERS, 3 rows each: LDS-only
// reads (P, w), global stores only -> their vmcnt FIFO never blocks a load.
__global__ __launch_bounds__(512, 4) void attn_main(
    const float* __restrict__ Qg, const float* __restrict__ wg,
    const uint32_t* __restrict__ bitsg, const unsigned short* __restrict__ vwtg,
    const unsigned short* __restrict__ kbfg, float* __restrict__ outg,
    float* __restrict__ pg) {
    extern __shared__ char smem[];
    char* Pb = smem;                          // [16][4096 B] bf16, 65536 B
    float* w_lds = (float*)(smem + 65536);    // [2048] f32, 8192 B
    float* red = (float*)(smem + 73728);      // [8][16]
    float* rinv_sh = (float*)(smem + 74240);  // [16]

    int bid = blockIdx.x;
    // XCD swizzle: 3072 WGs = 8 x 384 (3 heads per XCD), bijective
    int swz = (bid & 7) * 384 + (bid >> 3);
    int bh = swz >> 7;
    int qb = swz & 127;
    int b = bh / NH;
    int q0 = qb * 16;

    const unsigned short* kbfh = kbfg + (size_t)bh * NS * ND;
    const uint32_t* bitsb = bitsg + (size_t)b * (NS * (NS / 32));
    float* ph = pg + ((size_t)bh * NS + q0) * NS;
    float* outh = outg + (size_t)bh * NS * ND;

    int tid = threadIdx.x;
    int wv = tid >> 6, lane = tid & 63;
    int m = lane & 15, kb = lane >> 4;
    const int xm = (m & 7) << 4;

    // stage w into LDS (visible after the rms barrier)
    *(f32x4*)(w_lds + tid * 4) = *(const f32x4*)(wg + tid * 4);

    // Q fragments (B operand), 1/8 folded
    s16x8 qf[2];
#pragma unroll
    for (int ks = 0; ks < 2; ks++) {
        const float* src = Qg + ((size_t)bh * NS + q0 + m) * ND + ks * 32 + kb * 8;
        f32x4 a = *(const f32x4*)src;
        f32x4 c4 = *(const f32x4*)(src + 4);
        s16x8 f;
#pragma unroll
        for (int j = 0; j < 4; j++) {
            f[j] = f2bf(a[j] * 0.125f);
            f[4 + j] = f2bf(c4[j] * 0.125f);
        }
        qf[ks] = f;
    }

    // ---- Phase 1: QK over this wave's 256-k strip -> P (LDS) + ssum ----
    float ssum = 0.f;
    const int cbase = wv * 256;
#pragma unroll 4
    for (int kt = 0; kt < 16; kt++) {
        int krow = cbase + kt * 16;
        s16x8 kf0 = *(const s16x8*)(kbfh + (size_t)(krow + m) * ND + kb * 8);
        s16x8 kf1 = *(const s16x8*)(kbfh + (size_t)(krow + m) * ND + 32 + kb * 8);
        f32x4 c = {0.f, 0.f, 0.f, 0.f};
        c = mfma16(kf0, qf[0], c);
        c = mfma16(kf1, qf[1], c);
        int kcol = krow + kb * 4;
        uint32_t word = bitsb[(size_t)(q0 + m) * (NS / 32) + (kcol >> 5)];
        uint32_t keepbits = word >> (kcol & 31);
        float p[4];
#pragma unroll
        for (int r = 0; r < 4; r++) {
            float s = c[r];
            bool keep = ((keepbits >> r) & 1u) && (s > 0.f);
            p[r] = keep ? s : 0.f;
            ssum += p[r] * p[r];
        }
        uint2 u;
        u.x = (uint32_t)(unsigned short)f2bf(p[0]) |
              ((uint32_t)(unsigned short)f2bf(p[1]) << 16);
        u.y = (uint32_t)(unsigned short)f2bf(p[2]) |
              ((uint32_t)(unsigned short)f2bf(p[3]) << 16);
        *(uint2*)(Pb + m * 4096 + ((kcol * 2) ^ xm)) = u;
    }
    ssum += __shfl_xor(ssum, 16);
    ssum += __shfl_xor(ssum, 32);
    if (lane < 16) red[wv * 16 + lane] = ssum;
    __syncthreads();
    if (tid < 16) {
        float s = 0.f;
#pragma unroll
        for (int i = 0; i < 8; i++) s += red[i * 16 + tid];
        rinv_sh[tid] = 1.0f / sqrtf(s * (1.0f / NS) + 1e-6f);
    }
    __syncthreads();

    // stream one p_attn row: LDS reads + pure global stores (no global loads)
    auto stream_row = [&](int r) {
        float ri = rinv_sh[r];
        int xr = (r & 7) << 4;
#pragma unroll
        for (int it = 0; it < 8; it++) {
            int colf = it * 256 + lane * 4;
            uint2 u = *(const uint2*)(Pb + r * 4096 + ((colf * 2) ^ xr));
            f32x4 w4 = *(const f32x4*)(w_lds + colf);
            f32x4 o;
            o[0] = bf2f((short)(u.x & 0xffff)) * w4[0] * ri;
            o[1] = bf2f((short)(u.x >> 16)) * w4[1] * ri;
            o[2] = bf2f((short)(u.y & 0xffff)) * w4[2] * ri;
            o[3] = bf2f((short)(u.y >> 16)) * w4[3] * ri;
            *(f32x4*)(ph + (size_t)r * NS + colf) = o;
        }
    };

    // ---- Phase 2 ----
    if (wv < 4) {
        // PV: this wave owns d-tile [dt*16, +16) over ALL k; two acc chains
        const int dt = wv;
        const unsigned short* vrow = vwtg + ((size_t)bh * ND + dt * 16 + m) * NS;
        f32x4 accA = {0.f, 0.f, 0.f, 0.f}, accB = {0.f, 0.f, 0.f, 0.f};
#pragma unroll 4
        for (int ks = 0; ks < 32; ks++) {
            int k0 = ks * 64;
            s16x8 af0 = *(const s16x8*)(vrow + k0 + kb * 8);
            s16x8 af1 = *(const s16x8*)(vrow + k0 + 32 + kb * 8);
            s16x8 b0 = *(const s16x8*)(Pb + m * 4096 + ((k0 * 2 + kb * 16) ^ xm));
            s16x8 b1 = *(const s16x8*)(Pb + m * 4096 + (((k0 + 32) * 2 + kb * 16) ^ xm));
            accA = mfma16(af0, b0, accA);
            accB = mfma16(af1, b1, accB);
        }
        float ri = rinv_sh[m];
        f32x4 o = {(accA[0] + accB[0]) * ri, (accA[1] + accB[1]) * ri,
                   (accA[2] + accB[2]) * ri, (accA[3] + accB[3]) * ri};
        *(f32x4*)(outh + (size_t)(q0 + m) * ND + dt * 16 + kb * 4) = o;
        // then help stream: one row
        stream_row(12 + wv);
    } else {
        // PURE STREAMER: 3 rows, no global loads ever -> stores never drained
        int sv = wv - 4;
        stream_row(sv * 3);
        stream_row(sv * 3 + 1);
        stream_row(sv * 3 + 2);
    }
}

// ---------- fallback (no workspace): fp32-exact per-row kernel ----------
__global__ void attn_fallback(const float* __restrict__ Qg, const float* __restrict__ Kg,
                              const float* __restrict__ Vg, const int* __restrict__ maskg,
                              const float* __restrict__ wg, float* __restrict__ outg,
                              float* __restrict__ pg) {
    __shared__ float qs[64];
    __shared__ float srow[2048];
    __shared__ float osum[64];
    __shared__ float red2[8];
    int bid = blockIdx.x;
    int bh = bid >> 11, q = bid & 2047, b = bh / NH;
    int tid = threadIdx.x;
    const float* Qr = Qg + ((size_t)bh * NS + q) * ND;
    const float* Kh = Kg + (size_t)bh * NS * ND;
    const float* Vh = Vg + (size_t)bh * NS * ND;
    const int* mrow = maskg + ((size_t)b * NS + q) * NS;
    if (tid < 64) {
        qs[tid] = Qr[tid] * 0.125f;
        osum[tid] = 0.f;
    }
    __syncthreads();
    float ss = 0.f;
    for (int k = tid; k < NS; k += 256) {
        float s = 0.f;
        const float* kr = Kh + (size_t)k * ND;
        for (int d = 0; d < ND; d++) s += qs[d] * kr[d];
        if (mrow[k] == 0 || s < 0.f) s = 0.f;
        srow[k] = s;
        ss += s * s;
    }
#pragma unroll
    for (int o = 32; o >= 1; o >>= 1) ss += __shfl_down(ss, o);
    if ((tid & 63) == 0) red2[tid >> 6] = ss;
    __syncthreads();
    float ri;
    {
        float tot = red2[0] + red2[1] + red2[2] + red2[3];
        ri = 1.0f / sqrtf(tot * (1.0f / NS) + 1e-6f);
    }
    for (int k = tid; k < NS; k += 256) {
        float pa = srow[k] * ri * wg[k];
        pg[(((size_t)bh * NS + q) * NS) + k] = pa;
        const float* vr = Vh + (size_t)k * ND;
        for (int d = 0; d < ND; d++) atomicAdd(&osum[d], pa * vr[d]);
    }
    __syncthreads();
    if (tid < 64) outg[((size_t)bh * NS + q) * ND + tid] = osum[tid];
}

extern "C" void kernel_launch(void* const* d_in, const int* in_sizes, int n_in,
                              void* d_out, int out_size, void* d_ws, size_t ws_size,
                              hipStream_t stream) {
    const float* Q = (const float*)d_in[0];
    const float* K = (const float*)d_in[1];
    const float* V = (const float*)d_in[2];
    const int* mask = (const int*)d_in[3];
    const float* w = (const float*)d_in[4];
    float* out = (float*)d_out;
    float* pattn = out + (size_t)NB * NH * NS * ND;

    const size_t bits_bytes = (size_t)NB * NS * (NS / 32) * sizeof(uint32_t);     // 1 MB
    const size_t vwt_bytes = (size_t)NB * NH * ND * NS * sizeof(unsigned short);  // 6.3 MB
    const size_t kbf_bytes = vwt_bytes;                                           // 6.3 MB
    const int nwg = NB * NH * (NS / 16);  // 3072
    const int smem = 65536 + 8192 + 512 + 64;  // 74304 B

    if (ws_size >= bits_bytes + vwt_bytes + kbf_bytes) {
        char* wsb = (char*)d_ws;
        uint32_t* bits = (uint32_t*)wsb;
        unsigned short* vwt = (unsigned short*)(wsb + bits_bytes);
        unsigned short* kbf = (unsigned short*)(wsb + bits_bytes + vwt_bytes);
        kbits<<<(NB * NS * NS / 32) / 256, 256, 0, stream>>>(mask, bits);
        kcast<<<(NB * NH * NS * ND) / (256 * 8), 256, 0, stream>>>(K, kbf);
        kvwt<<<NB * NH * (NS / 32), 256, 0, stream>>>(V, w, vwt);
        hipFuncSetAttribute(reinterpret_cast<const void*>(&attn_main),
                            hipFuncAttributeMaxDynamicSharedMemorySize, smem);
        attn_main<<<nwg, 512, smem, stream>>>(Q, w, bits, vwt, kbf, out, pattn);
    } else {
        attn_fallback<<<NB * NH * NS, 256, 0, stream>>>(Q, K, V, mask, w, out, pattn);
    }
}